// Round 1
// baseline (3226.186 us; speedup 1.0000x reference)
//
#include <hip/hip_runtime.h>

// ---------------- types / helpers ----------------
typedef __attribute__((ext_vector_type(8))) short bf16x8;
typedef __attribute__((ext_vector_type(4))) float f32x4;

#define MFMA(a, b, c) __builtin_amdgcn_mfma_f32_16x16x32_bf16((a), (b), (c), 0, 0, 0)

__device__ inline short f2bf(float f) {
  unsigned u = __builtin_bit_cast(unsigned, f);
  u += 0x7fffu + ((u >> 16) & 1u);   // round-to-nearest-even
  return (short)(u >> 16);
}
__device__ inline float bf2f(short s) {
  unsigned u = ((unsigned)(unsigned short)s) << 16;
  return __builtin_bit_cast(float, u);
}
__device__ inline float sigm(float x) { return 1.f / (1.f + expf(-x)); }

// ---------------- sizes ----------------
#define B_SZ 1024
#define T_SZ 100

// ws layout (bytes)
#define O_GFK   0u
#define O_GFRK  (O_GFK  + 98304u)
#define O_LBK   (O_GFRK + 98304u)
#define O_LBRK  (O_LBK  + 131072u)
#define O_G2    (O_LBRK + 131072u)
#define O_L2    (O_G2   + 2359296u)
#define O_X     (O_L2   + 4194304u)     // [B][T][128] bf16
#define O_X1    (O_X    + 26214400u)    // [B][T][256] bf16
#define O_HG    (O_X1   + 52428800u)    // 2 x [B][512] bf16
#define O_HL    (O_HG   + 2097152u)     // 2 x [B][512] bf16
#define O_C     (O_HL   + 2097152u)     // [B][512] f32
#define O_MS    (O_C    + 2097152u)     // [B][512] f32

// ---------------- weight pack: dst[nt][kb][c][v] = W[kb*8+v][nt*16+c] (bf16) ----------------
__global__ void pack_b(const float* __restrict__ s1, int K1,
                       const float* __restrict__ s2, int K1p,
                       int Kp, int N, short* __restrict__ dst) {
  int i = blockIdx.x * 256 + threadIdx.x;
  int total = N * Kp;
  if (i >= total) return;
  int v = i & 7, c = (i >> 3) & 15, r = i >> 7;
  int kb8 = Kp >> 3;
  int kb = r % kb8, nt = r / kb8;
  int k = kb * 8 + v, col = nt * 16 + c;
  float val;
  if (k < K1p) val = (k < K1) ? s1[k * N + col] : 0.f;
  else         val = s2[(k - K1p) * N + col];
  dst[i] = f2bf(val);
}

// ---------------- embedding: x[b][t][0:100]=emb[text], pad to 128 with 0 ----------------
__global__ void embed_k(const int* __restrict__ text, const float* __restrict__ emb,
                        short* __restrict__ x) {
  int i = blockIdx.x * 256 + threadIdx.x;
  if (i >= B_SZ * T_SZ * 128) return;
  int col = i & 127, bt = i >> 7;
  float v = 0.f;
  if (col < 100) v = emb[text[bt] * 100 + col];
  x[i] = f2bf(v);
}

// ---------------- layer 1: persistent GRU(fwd) + LSTM(bwd), H=128 ----------------
// 128 wgs x 512 thr. wg<64: GRU rows [wg*16..); wg>=64: LSTM rows [(wg-64)*16..)
__global__ __launch_bounds__(512) void layer1_k(
    const short* __restrict__ x, const short* __restrict__ gfk,
    const short* __restrict__ gfrk, const float* __restrict__ gfb,
    const short* __restrict__ lbk, const short* __restrict__ lbrk,
    const float* __restrict__ lbb, short* __restrict__ x1) {
  __shared__ __attribute__((aligned(16))) short xst[16 * 136];
  __shared__ __attribute__((aligned(16))) short hst[16 * 136];
  const int wgid = blockIdx.x;
  const bool gru = wgid < 64;
  const int b0 = (gru ? wgid : wgid - 64) * 16;
  const int tid = threadIdx.x, lane = tid & 63, w = tid >> 6;
  const int c = lane & 15, g = lane >> 4;
  const int NS = gru ? 3 : 4;

  for (int i = tid; i < 16 * 136; i += 512) hst[i] = 0;

  const bf16x8* kp = (const bf16x8*)(gru ? gfk : lbk);
  const bf16x8* rp = (const bf16x8*)(gru ? gfrk : lbrk);

  // input-projection B-fragments in registers (K=128 -> 4 k-steps)
  bf16x8 kf[4][4];
  #pragma unroll
  for (int s = 0; s < 4; ++s)
    if (s < NS)
      #pragma unroll
      for (int ks = 0; ks < 4; ++ks)
        kf[s][ks] = kp[((s * 8 + w) * 16 + 4 * ks + g) * 16 + c];

  const int col = w * 16 + c;
  // biases for this lane's column
  float bz = 0, br_ = 0, bxh = 0, brh = 0, bi_ = 0, bf_ = 0, bc_ = 0, bo_ = 0;
  if (gru) {
    bz  = gfb[col]       + gfb[384 + col];
    br_ = gfb[128 + col] + gfb[512 + col];
    bxh = gfb[256 + col];
    brh = gfb[640 + col];
  } else {
    bi_ = lbb[col]; bf_ = lbb[128 + col]; bc_ = lbb[256 + col]; bo_ = lbb[384 + col];
  }

  float hreg[4] = {0.f, 0.f, 0.f, 0.f};
  float cst[4]  = {0.f, 0.f, 0.f, 0.f};

  for (int tt = 0; tt < T_SZ; ++tt) {
    const int t = gru ? tt : (T_SZ - 1 - tt);
    __syncthreads();
    if (tid < 256) {
      int row = tid >> 4, ch = tid & 15;
      *(bf16x8*)&xst[row * 136 + ch * 8] =
          *(const bf16x8*)&x[((b0 + row) * T_SZ + t) * 128 + ch * 8];
    }
    __syncthreads();

    f32x4 acc[4];
    #pragma unroll
    for (int s = 0; s < 4; ++s) acc[s] = (f32x4){0.f, 0.f, 0.f, 0.f};

    bf16x8 ax[4], ah[4];
    #pragma unroll
    for (int ks = 0; ks < 4; ++ks) {
      ax[ks] = *(const bf16x8*)&xst[c * 136 + ks * 32 + g * 8];
      ah[ks] = *(const bf16x8*)&hst[c * 136 + ks * 32 + g * 8];
    }
    #pragma unroll
    for (int s = 0; s < 4; ++s) {
      if (s < NS) {
        int dst = (gru && s == 2) ? 3 : s;   // GRU: keep x@k_h separate from h@rk_h
        #pragma unroll
        for (int ks = 0; ks < 4; ++ks) {
          acc[s] = MFMA(ax[ks], kf[s][ks], acc[s]);
          bf16x8 bh = rp[((s * 8 + w) * 16 + 4 * ks + g) * 16 + c];
          acc[dst] = MFMA(ah[ks], bh, acc[dst]);
        }
      }
    }
    __syncthreads();   // all reads of hst done before updating it

    if (gru) {
      #pragma unroll
      for (int j = 0; j < 4; ++j) {
        float z  = sigm(acc[0][j] + bz);
        float r  = sigm(acc[1][j] + br_);
        float hh = tanhf(acc[2][j] + bxh + r * (acc[3][j] + brh));
        float hn = z * hreg[j] + (1.f - z) * hh;
        hreg[j] = hn;
        short hb = f2bf(hn);
        int row = 4 * g + j;
        hst[row * 136 + col] = hb;
        x1[((b0 + row) * T_SZ + t) * 256 + col] = hb;
      }
    } else {
      #pragma unroll
      for (int j = 0; j < 4; ++j) {
        float i_ = acc[0][j] + bi_;
        float f_ = acc[1][j] + bf_;
        float cc = acc[2][j] + bc_;
        float o_ = acc[3][j] + bo_;
        float cn = sigm(f_) * cst[j] + sigm(i_) * tanhf(cc);
        cst[j] = cn;
        float hn = sigm(o_) * tanhf(cn);
        short hb = f2bf(hn);
        int row = 4 * g + j;
        hst[row * 136 + col] = hb;
        x1[((b0 + row) * T_SZ + t) * 256 + 128 + col] = hb;
      }
    }
  }
}

// ---------------- layer 2 step kernel (launch k: GRU2 step k || LSTM2 step k-1) ----------
// 256 wgs x 512 thr. wg<128: GRU2 (H2=512, K=256+512, N=1536); else LSTM2 (K=512+512, N=2048)
// wg tile: 64 rows x 64 h-cols. waves: 2M x 4N.
__global__ __launch_bounds__(512) void step_k(
    const short* __restrict__ x1, const short* __restrict__ G2p, const float* __restrict__ g2b,
    const short* __restrict__ L2p, const float* __restrict__ l2b,
    short* __restrict__ hg, short* __restrict__ hl,
    float* __restrict__ cbuf, float* __restrict__ msum, int k) {
  __shared__ __attribute__((aligned(16))) short Ast[64 * 1032];
  const int wgid = blockIdx.x;
  const bool gru = wgid < 128;
  if (gru && k > 99) return;
  if (!gru && k < 1) return;
  const int id = gru ? wgid : wgid - 128;
  const int rowwg = id >> 3, colwg = id & 7;
  const int b0 = rowwg * 64, H0 = colwg * 64;
  const int tid = threadIdx.x, lane = tid & 63, w = tid >> 6;
  const int c = lane & 15, g = lane >> 4;
  const int wm = w >> 2, wn = w & 3;

  if (gru) {
    const int t = k;
    const short* hprev = hg + ((size_t)((k - 1) & 1)) * 524288;
    // stage A = [x1[t] (256) | h_g (512)], row stride 776
    for (int it = 0; it < 4; ++it) {
      int idx = it * 512 + tid; int row = idx >> 5, ch = idx & 31;
      *(bf16x8*)&Ast[row * 776 + ch * 8] =
          *(const bf16x8*)&x1[((b0 + row) * T_SZ + t) * 256 + ch * 8];
    }
    for (int it = 0; it < 8; ++it) {
      int idx = it * 512 + tid; int row = idx >> 6, ch = idx & 63;
      *(bf16x8*)&Ast[row * 776 + 256 + ch * 8] =
          *(const bf16x8*)&hprev[(b0 + row) * 512 + ch * 8];
    }
    __syncthreads();

    f32x4 acc[2][4];
    #pragma unroll
    for (int mi = 0; mi < 2; ++mi)
      #pragma unroll
      for (int s = 0; s < 4; ++s) acc[mi][s] = (f32x4){0.f, 0.f, 0.f, 0.f};

    const bf16x8* Bp = (const bf16x8*)G2p;
    #pragma unroll 4
    for (int ks = 0; ks < 24; ++ks) {   // K=768
      bf16x8 a0 = *(const bf16x8*)&Ast[(2 * wm * 16 + c) * 776 + ks * 32 + g * 8];
      bf16x8 a1 = *(const bf16x8*)&Ast[((2 * wm + 1) * 16 + c) * 776 + ks * 32 + g * 8];
      #pragma unroll
      for (int s = 0; s < 3; ++s) {
        int nt = s * 32 + colwg * 4 + wn;
        bf16x8 b = Bp[(nt * 96 + 4 * ks + g) * 16 + c];
        int dst = (s == 2 && ks >= 8) ? 3 : s;   // split x@k_h (ks<8) from h@rk_h
        acc[0][dst] = MFMA(a0, b, acc[0][dst]);
        acc[1][dst] = MFMA(a1, b, acc[1][dst]);
      }
    }

    short* hout = hg + ((size_t)(k & 1)) * 524288;
    const int hcol = H0 + wn * 16 + c;
    #pragma unroll
    for (int mi = 0; mi < 2; ++mi)
      #pragma unroll
      for (int j = 0; j < 4; ++j) {
        int rl = (2 * wm + mi) * 16 + 4 * g + j;
        int rowg = b0 + rl;
        float z  = sigm(acc[mi][0][j] + g2b[hcol] + g2b[1536 + hcol]);
        float r  = sigm(acc[mi][1][j] + g2b[512 + hcol] + g2b[2048 + hcol]);
        float hh = tanhf(acc[mi][2][j] + g2b[1024 + hcol] +
                         r * (acc[mi][3][j] + g2b[2560 + hcol]));
        float hold = bf2f(Ast[rl * 776 + 256 + hcol]);
        float hn = z * hold + (1.f - z) * hh;
        hout[rowg * 512 + hcol] = f2bf(hn);
      }
  } else {
    const int t = k - 1;
    const short* xsrc = hg + ((size_t)(t & 1)) * 524288;          // x1g[t] = GRU2 out, written launch k-1
    const short* hprev = hl + ((size_t)((t - 1) & 1)) * 524288;
    // stage A = [x1g[t] (512) | h_l (512)], row stride 1032
    for (int it = 0; it < 8; ++it) {
      int idx = it * 512 + tid; int row = idx >> 6, ch = idx & 63;
      *(bf16x8*)&Ast[row * 1032 + ch * 8] =
          *(const bf16x8*)&xsrc[(b0 + row) * 512 + ch * 8];
    }
    for (int it = 0; it < 8; ++it) {
      int idx = it * 512 + tid; int row = idx >> 6, ch = idx & 63;
      *(bf16x8*)&Ast[row * 1032 + 512 + ch * 8] =
          *(const bf16x8*)&hprev[(b0 + row) * 512 + ch * 8];
    }
    __syncthreads();

    f32x4 acc[2][4];
    #pragma unroll
    for (int mi = 0; mi < 2; ++mi)
      #pragma unroll
      for (int s = 0; s < 4; ++s) acc[mi][s] = (f32x4){0.f, 0.f, 0.f, 0.f};

    const bf16x8* Bp = (const bf16x8*)L2p;
    #pragma unroll 4
    for (int ks = 0; ks < 32; ++ks) {   // K=1024
      bf16x8 a0 = *(const bf16x8*)&Ast[(2 * wm * 16 + c) * 1032 + ks * 32 + g * 8];
      bf16x8 a1 = *(const bf16x8*)&Ast[((2 * wm + 1) * 16 + c) * 1032 + ks * 32 + g * 8];
      #pragma unroll
      for (int s = 0; s < 4; ++s) {
        int nt = s * 32 + colwg * 4 + wn;
        bf16x8 b = Bp[(nt * 128 + 4 * ks + g) * 16 + c];
        acc[0][s] = MFMA(a0, b, acc[0][s]);
        acc[1][s] = MFMA(a1, b, acc[1][s]);
      }
    }

    short* hout = hl + ((size_t)(t & 1)) * 524288;
    const int hcol = H0 + wn * 16 + c;
    #pragma unroll
    for (int mi = 0; mi < 2; ++mi)
      #pragma unroll
      for (int j = 0; j < 4; ++j) {
        int rl = (2 * wm + mi) * 16 + 4 * g + j;
        int rowg = b0 + rl;
        int idxg = rowg * 512 + hcol;
        float i_ = acc[mi][0][j] + l2b[hcol];
        float f_ = acc[mi][1][j] + l2b[512 + hcol];
        float cc = acc[mi][2][j] + l2b[1024 + hcol];
        float o_ = acc[mi][3][j] + l2b[1536 + hcol];
        float cn = sigm(f_) * cbuf[idxg] + sigm(i_) * tanhf(cc);
        cbuf[idxg] = cn;
        float hn = sigm(o_) * tanhf(cn);
        hout[idxg] = f2bf(hn);
        msum[idxg] += hn;
      }
  }
}

// ---------------- head: mean -> MLP -> softmax/sigmoid ----------------
__global__ __launch_bounds__(256) void head_k(
    const float* __restrict__ msum, const float* __restrict__ upv,
    const float* __restrict__ fc1w, const float* __restrict__ fc1b,
    const float* __restrict__ d1w, const float* __restrict__ d1b,
    const float* __restrict__ d2w, const float* __restrict__ d2b,
    const float* __restrict__ d3w, const float* __restrict__ d3b,
    const float* __restrict__ rw, const float* __restrict__ rb,
    const float* __restrict__ cw, const float* __restrict__ cb,
    float* __restrict__ out) {
  __shared__ float h[1024], o1[64], o2[512], o3[128], lg[8];
  const int b = blockIdx.x, tid = threadIdx.x;
  const float u = upv[b];
  for (int i = tid; i < 512; i += 256) {
    h[i] = msum[b * 512 + i] * 0.01f;
    float v = u * fc1w[i] + fc1b[i];
    h[512 + i] = v > 0.f ? v : 0.f;
  }
  __syncthreads();
  if (tid < 64) {
    float a = d1b[tid];
    for (int i = 0; i < 1024; ++i) a += h[i] * d1w[i * 64 + tid];
    o1[tid] = a > 0.f ? a : 0.f;
  }
  __syncthreads();
  for (int j = tid; j < 512; j += 256) {
    float a = d2b[j];
    for (int i = 0; i < 64; ++i) a += o1[i] * d2w[i * 512 + j];
    o2[j] = a > 0.f ? a : 0.f;
  }
  __syncthreads();
  if (tid < 128) {
    float a = d3b[tid];
    for (int i = 0; i < 512; ++i) a += o2[i] * d3w[i * 128 + tid];
    o3[tid] = a > 0.f ? a : 0.f;
  }
  __syncthreads();
  if (tid < 5) {
    float a = rb[tid];
    for (int i = 0; i < 128; ++i) a += o3[i] * rw[i * 5 + tid];
    lg[tid] = a;
  }
  if (tid == 5) {
    float a = cb[0];
    for (int i = 0; i < 128; ++i) a += o3[i] * cw[i];
    out[5120 + b] = 1.f / (1.f + expf(-a));
  }
  __syncthreads();
  if (tid == 0) {
    float m = lg[0];
    for (int j = 1; j < 5; ++j) m = fmaxf(m, lg[j]);
    float e[5], s = 0.f;
    for (int j = 0; j < 5; ++j) { e[j] = expf(lg[j] - m); s += e[j]; }
    for (int j = 0; j < 5; ++j) out[b * 5 + j] = e[j] / s;
  }
}

// ---------------- launch ----------------
extern "C" void kernel_launch(void* const* d_in, const int* in_sizes, int n_in,
                              void* d_out, int out_size, void* d_ws, size_t ws_size,
                              hipStream_t stream) {
  const int*   text  = (const int*)  d_in[0];
  const float* upv   = (const float*)d_in[1];
  const float* emb   = (const float*)d_in[2];
  const float* gf_k  = (const float*)d_in[3];
  const float* gf_rk = (const float*)d_in[4];
  const float* gf_b  = (const float*)d_in[5];
  const float* lb_k  = (const float*)d_in[6];
  const float* lb_rk = (const float*)d_in[7];
  const float* lb_b  = (const float*)d_in[8];
  const float* g2_k  = (const float*)d_in[9];
  const float* g2_rk = (const float*)d_in[10];
  const float* g2_b  = (const float*)d_in[11];
  const float* l2_k  = (const float*)d_in[12];
  const float* l2_rk = (const float*)d_in[13];
  const float* l2_b  = (const float*)d_in[14];
  const float* fc1_w = (const float*)d_in[15];
  const float* fc1_b = (const float*)d_in[16];
  const float* d1_w  = (const float*)d_in[17];
  const float* d1_b  = (const float*)d_in[18];
  const float* d2_w  = (const float*)d_in[19];
  const float* d2_b  = (const float*)d_in[20];
  const float* d3_w  = (const float*)d_in[21];
  const float* d3_b  = (const float*)d_in[22];
  const float* rat_w = (const float*)d_in[23];
  const float* rat_b = (const float*)d_in[24];
  const float* rec_w = (const float*)d_in[25];
  const float* rec_b = (const float*)d_in[26];

  char* ws = (char*)d_ws;
  short* gfkp  = (short*)(ws + O_GFK);
  short* gfrkp = (short*)(ws + O_GFRK);
  short* lbkp  = (short*)(ws + O_LBK);
  short* lbrkp = (short*)(ws + O_LBRK);
  short* G2p   = (short*)(ws + O_G2);
  short* L2p   = (short*)(ws + O_L2);
  short* xb    = (short*)(ws + O_X);
  short* x1    = (short*)(ws + O_X1);
  short* hg    = (short*)(ws + O_HG);
  short* hl    = (short*)(ws + O_HL);
  float* cbuf  = (float*)(ws + O_C);
  float* msum  = (float*)(ws + O_MS);

  // pack weights (bf16 B-fragment panels)
  pack_b<<<192, 256, 0, stream>>>(gf_k, 100, gf_k, 128, 128, 384, gfkp);
  pack_b<<<192, 256, 0, stream>>>(gf_rk, 128, gf_rk, 128, 128, 384, gfrkp);
  pack_b<<<256, 256, 0, stream>>>(lb_k, 100, lb_k, 128, 128, 512, lbkp);
  pack_b<<<256, 256, 0, stream>>>(lb_rk, 128, lb_rk, 128, 128, 512, lbrkp);
  pack_b<<<4608, 256, 0, stream>>>(g2_k, 256, g2_rk, 256, 768, 1536, G2p);
  pack_b<<<8192, 256, 0, stream>>>(l2_k, 512, l2_rk, 512, 1024, 2048, L2p);

  embed_k<<<51200, 256, 0, stream>>>(text, emb, xb);

  // zero initial states / accumulators
  hipMemsetAsync(ws + O_HG + 1048576u, 0, 1048576u, stream);  // hg[1]
  hipMemsetAsync(ws + O_HL + 1048576u, 0, 1048576u, stream);  // hl[1]
  hipMemsetAsync(ws + O_C, 0, 2097152u, stream);              // c
  hipMemsetAsync(ws + O_MS, 0, 2097152u, stream);             // msum

  layer1_k<<<128, 512, 0, stream>>>(xb, gfkp, gfrkp, gf_b, lbkp, lbrkp, lb_b, x1);

  for (int k = 0; k <= 100; ++k)
    step_k<<<256, 512, 0, stream>>>(x1, G2p, g2_b, L2p, l2_b, hg, hl, cbuf, msum, k);

  head_k<<<1024, 256, 0, stream>>>(msum, upv, fc1_w, fc1_b, d1_w, d1_b, d2_w, d2_b,
                                   d3_w, d3_b, rat_w, rat_b, rec_w, rec_b,
                                   (float*)d_out);
}